// Round 3
// baseline (469.507 us; speedup 1.0000x reference)
//
#include <hip/hip_runtime.h>

#define IN_H   1024
#define IN_W   1024
#define TILE_X 128
#define TILE_Y 64
#define LDS_H  70     // TILE_Y + 6 halo rows
#define LDS_W  136    // 1 pad col + 134 needed cols, rounded to 34 float4
#define ROW_F4 34
#define NF4    (LDS_H * ROW_F4)   // 2380 float4 stage elements

typedef __attribute__((address_space(1))) const void* gvoid_p;
typedef __attribute__((address_space(3))) void*       lvoid_p;

__global__ __launch_bounds__(256, 4)
void conv7x7_kernel(const float* __restrict__ X,
                    const float* __restrict__ W,
                    float* __restrict__ out) {
    __shared__ float lds[LDS_H * LDS_W];

    const int tid = threadIdx.x;
    const int x0  = blockIdx.x * TILE_X;
    const int y0  = blockIdx.y * TILE_Y;
    const int b   = blockIdx.z;

    const float* Ximg = X + (size_t)b * IN_H * IN_W;

    // LDS col 0 = global col x0-4 (3-halo plus one alignment col)
    // LDS row 0 = global row y0-3
    const int gx = x0 - 4;
    const int gy = y0 - 3;

    // ---- Weights: force into SGPRs (uniform) so fmacs read SGPR src0 ----
    float w[49];
    #pragma unroll
    for (int k = 0; k < 49; ++k)
        w[k] = __uint_as_float(__builtin_amdgcn_readfirstlane(__float_as_uint(W[k])));

    const bool interior = (gx >= 0) && (gx + LDS_W <= IN_W) &&
                          (gy >= 0) && (gy + LDS_H <= IN_H);

    if (interior) {
        // Direct global->LDS DMA, 16B per lane. LDS dest = linear i*16 bytes,
        // which is wave-uniform-base + laneid*16 for consecutive tid -> valid.
        for (int i = tid; i < NF4; i += 256) {
            int r = i / ROW_F4;
            int c = i - r * ROW_F4;
            const float* src = Ximg + (size_t)(gy + r) * IN_W + (gx + c * 4);
            __builtin_amdgcn_global_load_lds((gvoid_p)src, (lvoid_p)&lds[i * 4],
                                             16, 0, 0);
        }
    } else {
        for (int i = tid; i < NF4; i += 256) {
            int r   = i / ROW_F4;
            int c   = i - r * ROW_F4;
            int row = gy + r;
            float4 v = make_float4(0.f, 0.f, 0.f, 0.f);
            if (row >= 0 && row < IN_H) {
                const float* p = Ximg + (size_t)row * IN_W;
                int col = gx + c * 4;
                v.x = (col + 0 >= 0 && col + 0 < IN_W) ? p[col + 0] : 0.f;
                v.y = (col + 1 >= 0 && col + 1 < IN_W) ? p[col + 1] : 0.f;
                v.z = (col + 2 >= 0 && col + 2 < IN_W) ? p[col + 2] : 0.f;
                v.w = (col + 3 >= 0 && col + 3 < IN_W) ? p[col + 3] : 0.f;
            }
            *(float4*)&lds[r * LDS_W + c * 4] = v;
        }
    }

    __syncthreads();

    // ---- Compute: thread tile 4 wide x 8 tall ----
    const int tx = tid & 31;   // 32 thread-cols * 4 outputs = 128
    const int ty = tid >> 5;   // 8 thread-rows  * 8 outputs = 64

    float acc[8][4];
    #pragma unroll
    for (int o = 0; o < 8; ++o)
        #pragma unroll
        for (int c = 0; c < 4; ++c) acc[o][c] = 0.f;

    const int base_col = tx * 4;

    #pragma unroll
    for (int r = 0; r < 14; ++r) {   // 14 input rows feed 8 output rows
        const float* row = &lds[(ty * 8 + r) * LDS_W + base_col];
        // three aligned 16B LDS reads -> s[0..11]; needed window is s[1..10]
        float4 a  = *(const float4*)(row);
        float4 bq = *(const float4*)(row + 4);
        float4 cq = *(const float4*)(row + 8);
        float s[12] = { a.x, a.y, a.z, a.w,
                        bq.x, bq.y, bq.z, bq.w,
                        cq.x, cq.y, cq.z, cq.w };
        #pragma unroll
        for (int o = 0; o < 8; ++o) {
            const int ky = r - o;
            if (ky >= 0 && ky < 7) {
                #pragma unroll
                for (int kx = 0; kx < 7; ++kx) {
                    const float wv = w[ky * 7 + kx];
                    #pragma unroll
                    for (int c = 0; c < 4; ++c)
                        acc[o][c] += wv * s[1 + c + kx];
                }
            }
        }
    }

    float* Oimg = out + (size_t)b * IN_H * IN_W;
    const int ox = x0 + tx * 4;
    #pragma unroll
    for (int o = 0; o < 8; ++o) {
        const int oy = y0 + ty * 8 + o;
        float4 v = make_float4(acc[o][0], acc[o][1], acc[o][2], acc[o][3]);
        *(float4*)(Oimg + (size_t)oy * IN_W + ox) = v;
    }
}

extern "C" void kernel_launch(void* const* d_in, const int* in_sizes, int n_in,
                              void* d_out, int out_size, void* d_ws, size_t ws_size,
                              hipStream_t stream) {
    const float* X = (const float*)d_in[0];
    const float* W = (const float*)d_in[1];
    float* out = (float*)d_out;

    dim3 grid(IN_W / TILE_X, IN_H / TILE_Y, 64);
    conv7x7_kernel<<<grid, 256, 0, stream>>>(X, W, out);
}

// Round 7
// 467.258 us; speedup vs baseline: 1.0048x; 1.0048x over previous
//
#include <hip/hip_runtime.h>

#define IN_H   1024
#define IN_W   1024
#define TILE_X 128
#define TILE_Y 32
#define LDS_H  38     // TILE_Y + 6 halo rows
#define LDS_W  136    // 1 pad col + 134 needed cols, rounded to 34 float4
#define ROW_F4 34
#define NF4    (LDS_H * ROW_F4)   // 1292 float4 stage elements

typedef __attribute__((address_space(1))) const void* gvoid_p;
typedef __attribute__((address_space(3))) void*       lvoid_p;

__global__ __launch_bounds__(256, 7)
void conv7x7_kernel(const float* __restrict__ X,
                    const float* __restrict__ W,
                    float* __restrict__ out) {
    __shared__ float lds[LDS_H * LDS_W];

    const int tid = threadIdx.x;
    const int x0  = blockIdx.x * TILE_X;
    const int y0  = blockIdx.y * TILE_Y;
    const int b   = blockIdx.z;

    const float* Ximg = X + (size_t)b * IN_H * IN_W;

    // LDS col 0 = global col x0-4 (3-halo plus one alignment col)
    // LDS row 0 = global row y0-3
    const int gx = x0 - 4;
    const int gy = y0 - 3;

    // ---- Weights: force into SGPRs (uniform) so fmacs read SGPR src0 ----
    float w[49];
    #pragma unroll
    for (int k = 0; k < 49; ++k)
        w[k] = __uint_as_float(__builtin_amdgcn_readfirstlane(__float_as_uint(W[k])));

    const bool interior = (gx >= 0) && (gx + LDS_W <= IN_W) &&
                          (gy >= 0) && (gy + LDS_H <= IN_H);

    if (interior) {
        // Direct global->LDS DMA, 16B per lane. LDS dest = linear i*16 bytes,
        // which is wave-uniform-base + laneid*16 for consecutive tid -> valid.
        for (int i = tid; i < NF4; i += 256) {
            int r = i / ROW_F4;
            int c = i - r * ROW_F4;
            const float* src = Ximg + (size_t)(gy + r) * IN_W + (gx + c * 4);
            __builtin_amdgcn_global_load_lds((gvoid_p)src, (lvoid_p)&lds[i * 4],
                                             16, 0, 0);
        }
    } else {
        for (int i = tid; i < NF4; i += 256) {
            int r   = i / ROW_F4;
            int c   = i - r * ROW_F4;
            int row = gy + r;
            float4 v = make_float4(0.f, 0.f, 0.f, 0.f);
            if (row >= 0 && row < IN_H) {
                const float* p = Ximg + (size_t)row * IN_W;
                int col = gx + c * 4;
                v.x = (col + 0 >= 0 && col + 0 < IN_W) ? p[col + 0] : 0.f;
                v.y = (col + 1 >= 0 && col + 1 < IN_W) ? p[col + 1] : 0.f;
                v.z = (col + 2 >= 0 && col + 2 < IN_W) ? p[col + 2] : 0.f;
                v.w = (col + 3 >= 0 && col + 3 < IN_W) ? p[col + 3] : 0.f;
            }
            *(float4*)&lds[r * LDS_W + c * 4] = v;
        }
    }

    __syncthreads();

    // ---- Compute: thread tile 4 wide x 4 tall ----
    const int tx  = tid & 31;   // 32 thread-cols * 4 outputs = 128
    const int tyq = tid >> 5;   // 8 thread-rows  * 4 outputs = 32

    float acc[4][4];
    #pragma unroll
    for (int o = 0; o < 4; ++o)
        #pragma unroll
        for (int c = 0; c < 4; ++c) acc[o][c] = 0.f;

    const int base_col = tx * 4;

    #pragma unroll
    for (int r = 0; r < 10; ++r) {   // 10 input rows feed 4 output rows
        const float* row = &lds[(tyq * 4 + r) * LDS_W + base_col];
        // three aligned 16B LDS reads -> s[0..11]; needed window is s[1..10]
        float4 a  = *(const float4*)(row);
        float4 bq = *(const float4*)(row + 4);
        float4 cq = *(const float4*)(row + 8);
        float s[12] = { a.x, a.y, a.z, a.w,
                        bq.x, bq.y, bq.z, bq.w,
                        cq.x, cq.y, cq.z, cq.w };
        #pragma unroll
        for (int o = 0; o < 4; ++o) {
            const int ky = r - o;
            if (ky >= 0 && ky < 7) {
                #pragma unroll
                for (int kx = 0; kx < 7; ++kx) {
                    const float wv = w[ky * 7 + kx];
                    #pragma unroll
                    for (int c = 0; c < 4; ++c)
                        acc[o][c] += wv * s[1 + c + kx];
                }
            }
        }
    }

    float* Oimg = out + (size_t)b * IN_H * IN_W;
    const int ox = x0 + tx * 4;
    #pragma unroll
    for (int o = 0; o < 4; ++o) {
        const int oy = y0 + tyq * 4 + o;
        float4 v = make_float4(acc[o][0], acc[o][1], acc[o][2], acc[o][3]);
        *(float4*)(Oimg + (size_t)oy * IN_W + ox) = v;
    }
}

extern "C" void kernel_launch(void* const* d_in, const int* in_sizes, int n_in,
                              void* d_out, int out_size, void* d_ws, size_t ws_size,
                              hipStream_t stream) {
    const float* X = (const float*)d_in[0];
    const float* W = (const float*)d_in[1];
    float* out = (float*)d_out;

    dim3 grid(IN_W / TILE_X, IN_H / TILE_Y, 64);
    conv7x7_kernel<<<grid, 256, 0, stream>>>(X, W, out);
}